// Round 1
// baseline (319.123 us; speedup 1.0000x reference)
//
#include <hip/hip_runtime.h>
#include <hip/hip_bf16.h>

typedef unsigned short u16;
typedef unsigned int u32;
typedef __attribute__((ext_vector_type(8))) short bf16x8;
typedef __attribute__((ext_vector_type(4))) float f32x4;

#define NEXP 8
#define NTOK 4096
#define DDIM 1024
#define MAX_TILES 80

__device__ __forceinline__ float bf2f(u16 u) { return __uint_as_float(((u32)u) << 16); }
__device__ __forceinline__ u16 f2bf(float f) {
    u32 u = __float_as_uint(f);
    u += 0x7fff + ((u >> 16) & 1);  // RNE
    return (u16)(u >> 16);
}

__device__ __forceinline__ void gload16(const void* g, void* l) {
    __builtin_amdgcn_global_load_lds((const __attribute__((address_space(1))) u32*)g,
                                     (__attribute__((address_space(3))) u32*)l, 16, 0, 0);
}

// ---------------- fp32 -> bf16 convert (vectorized, 8 elems/thread/iter) ----------------
__global__ __launch_bounds__(256) void cvt_bf16_kernel(const float* __restrict__ in,
                                                       u16* __restrict__ out, int n8) {
    int stride = gridDim.x * blockDim.x;
    for (int i = blockIdx.x * blockDim.x + threadIdx.x; i < n8; i += stride) {
        const float4* p = (const float4*)in + (size_t)i * 2;
        float4 a = p[0], b = p[1];
        uint4 o;
        o.x = (u32)f2bf(a.x) | ((u32)f2bf(a.y) << 16);
        o.y = (u32)f2bf(a.z) | ((u32)f2bf(a.w) << 16);
        o.z = (u32)f2bf(b.x) | ((u32)f2bf(b.y) << 16);
        o.w = (u32)f2bf(b.z) | ((u32)f2bf(b.w) << 16);
        *(uint4*)(out + (size_t)i * 8) = o;
    }
}

// ---------------- gating: scores -> softmax -> top2 -------------------------------------
// ctl layout (ints): [0..8) counts, [8..16) cursors, [16..25) offsets, [25] ntiles,
//                    [32..112) tile_expert, [112..192) tile_rowbase, [192..272) tile_segend
__global__ __launch_bounds__(256) void gate_kernel(const float* __restrict__ x,
                                                   const float* __restrict__ gw,
                                                   int* __restrict__ t2i, float* __restrict__ t2w,
                                                   int* __restrict__ ctl) {
    __shared__ float sgw[NEXP * DDIM];  // 32 KB
    for (int i = threadIdx.x; i < NEXP * DDIM; i += 256) sgw[i] = gw[i];
    __syncthreads();
    int t = blockIdx.x * 256 + threadIdx.x;
    float acc[NEXP];
#pragma unroll
    for (int e = 0; e < NEXP; e++) acc[e] = 0.f;
    const float4* xr = (const float4*)(x + (size_t)t * DDIM);
    for (int q = 0; q < DDIM / 4; q++) {
        float4 v = xr[q];
#pragma unroll
        for (int e = 0; e < NEXP; e++) {
            float4 g = *(const float4*)&sgw[e * DDIM + q * 4];
            acc[e] += v.x * g.x + v.y * g.y + v.z * g.z + v.w * g.w;
        }
    }
    float m = acc[0];
#pragma unroll
    for (int e = 1; e < NEXP; e++) m = fmaxf(m, acc[e]);
    float p[NEXP]; float s = 0.f;
#pragma unroll
    for (int e = 0; e < NEXP; e++) { p[e] = __expf(acc[e] - m); s += p[e]; }
    float inv = 1.f / s;
    float best = -1.f, sec = -1.f; int bi = 0, si = 0;
#pragma unroll
    for (int e = 0; e < NEXP; e++) {
        float pe = p[e] * inv;
        if (pe > best) { sec = best; si = bi; best = pe; bi = e; }
        else if (pe > sec) { sec = pe; si = e; }
    }
    t2i[2 * t] = bi;  t2i[2 * t + 1] = si;
    t2w[2 * t] = best; t2w[2 * t + 1] = sec;
    atomicAdd(&ctl[bi], 1);
    atomicAdd(&ctl[si], 1);
}

// ---------------- schedule: prefix offsets + row-tile list (single thread) --------------
__global__ void schedule_kernel(int* ctl) {
    int* counts = ctl;
    int* cursors = ctl + 8;
    int* offs = ctl + 16;
    int* te = ctl + 32;
    int* tr = ctl + 112;
    int* ts = ctl + 192;
    int o = 0, tt = 0;
    for (int e = 0; e < NEXP; e++) {
        offs[e] = o;
        int n = counts[e];
        for (int r = 0; r < n; r += 128) { te[tt] = e; tr[tt] = o + r; ts[tt] = o + n; tt++; }
        cursors[e] = 0;
        o += n;
    }
    offs[8] = o;
    ctl[25] = tt;
}

// ---------------- scatter: assign slots ------------------------------------------------
__global__ __launch_bounds__(256) void scatter_kernel(const int* __restrict__ t2i,
                                                      const float* __restrict__ t2w,
                                                      int* ctl, int* __restrict__ slot_token,
                                                      float* __restrict__ slot_wt) {
    int t = blockIdx.x * 256 + threadIdx.x;
    int* cursors = ctl + 8;
    const int* offs = ctl + 16;
#pragma unroll
    for (int k = 0; k < 2; k++) {
        int e = t2i[2 * t + k];
        int pos = atomicAdd(&cursors[e], 1);
        int slot = offs[e] + pos;
        slot_token[slot] = t;
        slot_wt[slot] = t2w[2 * t + k];
    }
}

// ---------------- expert GEMMs ----------------------------------------------------------
// MODE 0: H=Xg@w1^T, G=Xg@w3^T (dual acc), A = silu(H)*G -> Abuf bf16.  BN=64.
// MODE 1: Y = Abuf@w2^T, epilogue unsafeAtomicAdd(w * Y) into y fp32.   BN=128.
template <int MODE>
__global__ __launch_bounds__(256, 2) void moe_gemm_kernel(
    const u16* __restrict__ Amat, const u16* __restrict__ B1g, const u16* __restrict__ B2g,
    u16* __restrict__ OutB, float* __restrict__ OutY,
    const int* __restrict__ ctl, const int* __restrict__ slot_token,
    const float* __restrict__ slot_wt) {
    constexpr int BN = (MODE == 0) ? 64 : 128;
    constexpr int NB = BN / 32;   // B frags per wave
    constexpr int BL = BN / 32;   // B wave-loads per wave per K-step
    constexpr int BK = 64;
    constexpr int NK = DDIM / BK; // 16

    int tt = blockIdx.x;
    if (tt >= ctl[25]) return;
    int e = ctl[32 + tt];
    int rowbase = ctl[112 + tt];
    int segend = ctl[192 + tt];
    int cb = blockIdx.y;

    __shared__ __align__(16) u16 smem[2 * 128 * 64 + 2 * BN * 64 + ((MODE == 0) ? 2 * 64 * 64 : 0)];
    u16* sA = smem;                  // [2][128][64]
    u16* sB1 = smem + 2 * 128 * 64;  // [2][BN][64]
    u16* sB2 = sB1 + 2 * BN * 64;    // [2][64][64] (MODE 0 only)

    int tid = threadIdx.x;
    int lane = tid & 63;
    int wv = tid >> 6;
    int wrow = wv >> 1, wcol = wv & 1;
    int lr = lane >> 3;        // row within 8-row staging group
    int lc = (lane & 7) * 8;   // elem col within 64

    // Precompute gathered A source rows (4 staging loads per wave)
    size_t rowA[4];
#pragma unroll
    for (int i = 0; i < 4; i++) {
        int slot = rowbase + wv * 32 + i * 8 + lr;
        if (slot >= segend) slot = rowbase;
        int src = (MODE == 0) ? slot_token[slot] : slot;
        rowA[i] = (size_t)src * 1024;
    }
    size_t rowB[BL];
#pragma unroll
    for (int i = 0; i < BL; i++) {
        int r = cb * BN + wv * (BN / 4) + i * 8 + lr;
        rowB[i] = (size_t)e * 1048576 + (size_t)r * 1024;
    }

    f32x4 accH[4][NB], accG[4][NB];
    f32x4 zero = {0.f, 0.f, 0.f, 0.f};
#pragma unroll
    for (int m2 = 0; m2 < 4; m2++)
#pragma unroll
        for (int n = 0; n < NB; n++) { accH[m2][n] = zero; accG[m2][n] = zero; }

    auto stage = [&](int buf, int kt) {
        int k0 = kt * BK;
#pragma unroll
        for (int i = 0; i < 4; i++)
            gload16(Amat + rowA[i] + k0 + lc, sA + (size_t)buf * (128 * 64) + (wv * 32 + i * 8) * 64);
#pragma unroll
        for (int i = 0; i < BL; i++)
            gload16(B1g + rowB[i] + k0 + lc, sB1 + (size_t)buf * (BN * 64) + (wv * (BN / 4) + i * 8) * 64);
        if constexpr (MODE == 0) {
#pragma unroll
            for (int i = 0; i < BL; i++)
                gload16(B2g + rowB[i] + k0 + lc, sB2 + (size_t)buf * (BN * 64) + (wv * (BN / 4) + i * 8) * 64);
        }
    };

    auto compute = [&](int buf) {
#pragma unroll
        for (int kk = 0; kk < 2; kk++) {
            bf16x8 av[4];
#pragma unroll
            for (int m2 = 0; m2 < 4; m2++) {
                int r = wrow * 64 + m2 * 16 + (lane & 15);
                av[m2] = *(const bf16x8*)(sA + buf * (128 * 64) + r * 64 + kk * 32 + (lane >> 4) * 8);
            }
            bf16x8 b1v[NB];
#pragma unroll
            for (int n = 0; n < NB; n++) {
                int r = wcol * (BN / 2) + n * 16 + (lane & 15);
                b1v[n] = *(const bf16x8*)(sB1 + buf * (BN * 64) + r * 64 + kk * 32 + (lane >> 4) * 8);
            }
            if constexpr (MODE == 0) {
                bf16x8 b2v[NB];
#pragma unroll
                for (int n = 0; n < NB; n++) {
                    int r = wcol * (BN / 2) + n * 16 + (lane & 15);
                    b2v[n] = *(const bf16x8*)(sB2 + buf * (BN * 64) + r * 64 + kk * 32 + (lane >> 4) * 8);
                }
#pragma unroll
                for (int m2 = 0; m2 < 4; m2++)
#pragma unroll
                    for (int n = 0; n < NB; n++) {
                        accH[m2][n] = __builtin_amdgcn_mfma_f32_16x16x32_bf16(av[m2], b1v[n], accH[m2][n], 0, 0, 0);
                        accG[m2][n] = __builtin_amdgcn_mfma_f32_16x16x32_bf16(av[m2], b2v[n], accG[m2][n], 0, 0, 0);
                    }
            } else {
#pragma unroll
                for (int m2 = 0; m2 < 4; m2++)
#pragma unroll
                    for (int n = 0; n < NB; n++)
                        accH[m2][n] = __builtin_amdgcn_mfma_f32_16x16x32_bf16(av[m2], b1v[n], accH[m2][n], 0, 0, 0);
            }
        }
    };

    stage(0, 0);
    for (int kt = 0; kt < NK; ++kt) {
        __syncthreads();
        if (kt + 1 < NK) stage((kt + 1) & 1, kt + 1);
        compute(kt & 1);
    }

    // Epilogue. C/D layout: col = lane&15, row = (lane>>4)*4 + j  [learn_hip m89]
    int colblock = cb * BN + wcol * (BN / 2);
#pragma unroll
    for (int m2 = 0; m2 < 4; m2++) {
        int slotbase = rowbase + wrow * 64 + m2 * 16 + (lane >> 4) * 4;
#pragma unroll
        for (int n = 0; n < NB; n++) {
            int col = colblock + n * 16 + (lane & 15);
#pragma unroll
            for (int j = 0; j < 4; j++) {
                int slot = slotbase + j;
                if (slot < segend) {
                    if constexpr (MODE == 0) {
                        float h = accH[m2][n][j], g = accG[m2][n][j];
                        float a = (h / (1.f + __expf(-h))) * g;  // silu(h)*g
                        OutB[(size_t)slot * 1024 + col] = f2bf(a);
                    } else {
                        int tok = slot_token[slot];
                        float wgt = slot_wt[slot];
                        unsafeAtomicAdd(&OutY[(size_t)tok * 1024 + col], accH[m2][n][j] * wgt);
                    }
                }
            }
        }
    }
}

// ---------------- launch ----------------------------------------------------------------
extern "C" void kernel_launch(void* const* d_in, const int* in_sizes, int n_in,
                              void* d_out, int out_size, void* d_ws, size_t ws_size,
                              hipStream_t stream) {
    const float* x  = (const float*)d_in[0];
    const float* gw = (const float*)d_in[1];
    const float* w1 = (const float*)d_in[2];
    const float* w3 = (const float*)d_in[3];
    const float* w2 = (const float*)d_in[4];
    float* y = (float*)d_out;
    char* ws = (char*)d_ws;

    int*   ctl        = (int*)ws;                    // 4 KB control block
    int*   t2i        = (int*)(ws + 4096);           // 32 KB
    float* t2w        = (float*)(ws + 4096 + 32768);
    int*   slot_token = (int*)(ws + 4096 + 65536);
    float* slot_wt    = (float*)(ws + 4096 + 98304);
    u16*   xb   = (u16*)(ws + 262144);               // 4M elems
    u16*   w1b  = xb  + (size_t)4194304;             // 8M elems each
    u16*   w3b  = w1b + (size_t)8388608;
    u16*   w2b  = w3b + (size_t)8388608;
    u16*   Abuf = w2b + (size_t)8388608;             // 8192 x 1024 bf16

    hipMemsetAsync(ctl, 0, 4096, stream);
    hipMemsetAsync(y, 0, (size_t)out_size * sizeof(float), stream);

    cvt_bf16_kernel<<<2048, 256, 0, stream>>>(x,  xb,  4194304 / 8);
    cvt_bf16_kernel<<<2048, 256, 0, stream>>>(w1, w1b, 8388608 / 8);
    cvt_bf16_kernel<<<2048, 256, 0, stream>>>(w3, w3b, 8388608 / 8);
    cvt_bf16_kernel<<<2048, 256, 0, stream>>>(w2, w2b, 8388608 / 8);

    gate_kernel<<<16, 256, 0, stream>>>(x, gw, t2i, t2w, ctl);
    schedule_kernel<<<1, 1, 0, stream>>>(ctl);
    scatter_kernel<<<16, 256, 0, stream>>>(t2i, t2w, ctl, slot_token, slot_wt);

    moe_gemm_kernel<0><<<dim3(MAX_TILES, 16), 256, 0, stream>>>(
        xb, w1b, w3b, Abuf, nullptr, ctl, slot_token, slot_wt);
    moe_gemm_kernel<1><<<dim3(MAX_TILES, 8), 256, 0, stream>>>(
        Abuf, w2b, nullptr, nullptr, y, ctl, slot_token, slot_wt);
}

// Round 2
// 305.225 us; speedup vs baseline: 1.0455x; 1.0455x over previous
//
#include <hip/hip_runtime.h>
#include <hip/hip_bf16.h>

typedef unsigned short u16;
typedef unsigned int u32;
typedef __attribute__((ext_vector_type(8))) short bf16x8;
typedef __attribute__((ext_vector_type(4))) float f32x4;

#define NEXP 8
#define NTOK 4096
#define DDIM 1024
#define MAX_TILES 80

__device__ __forceinline__ float bf2f(u16 u) { return __uint_as_float(((u32)u) << 16); }
__device__ __forceinline__ u16 f2bf(float f) {
    u32 u = __float_as_uint(f);
    u += 0x7fff + ((u >> 16) & 1);  // RNE
    return (u16)(u >> 16);
}

__device__ __forceinline__ void gload16(const void* g, void* l) {
    __builtin_amdgcn_global_load_lds((const __attribute__((address_space(1))) u32*)g,
                                     (__attribute__((address_space(3))) u32*)l, 16, 0, 0);
}

// ---------------- fused fp32 -> bf16 convert for x,w1,w3,w2 (contig output) -------------
// ranges (in 8-elem chunks): x 512K, w1 1M, w3 1M, w2 1M  (total 3.5M chunks)
__global__ __launch_bounds__(256) void cvt_all_kernel(const float* __restrict__ x,
                                                      const float* __restrict__ w1,
                                                      const float* __restrict__ w3,
                                                      const float* __restrict__ w2,
                                                      u16* __restrict__ out) {
    const int N8 = 3670016;  // 28M / 8
    int stride = gridDim.x * blockDim.x;
    for (int i = blockIdx.x * blockDim.x + threadIdx.x; i < N8; i += stride) {
        const float* src;
        if (i < 524288)        src = x  + (size_t)i * 8;
        else if (i < 1572864)  src = w1 + ((size_t)i - 524288) * 8;
        else if (i < 2621440)  src = w3 + ((size_t)i - 1572864) * 8;
        else                   src = w2 + ((size_t)i - 2621440) * 8;
        float4 a = ((const float4*)src)[0], b = ((const float4*)src)[1];
        uint4 o;
        o.x = (u32)f2bf(a.x) | ((u32)f2bf(a.y) << 16);
        o.y = (u32)f2bf(a.z) | ((u32)f2bf(a.w) << 16);
        o.z = (u32)f2bf(b.x) | ((u32)f2bf(b.y) << 16);
        o.w = (u32)f2bf(b.z) | ((u32)f2bf(b.w) << 16);
        *(uint4*)(out + (size_t)i * 8) = o;
    }
}

// ---------------- gating: scores -> softmax -> top2 -------------------------------------
// ctl layout (ints): [0..8) counts, [8..16) cursors, [16..25) offsets, [25] ntiles,
//                    [32..112) tile_expert, [112..192) tile_rowbase, [192..272) tile_segend
__global__ __launch_bounds__(256) void gate_kernel(const float* __restrict__ x,
                                                   const float* __restrict__ gw,
                                                   int* __restrict__ t2i, float* __restrict__ t2w,
                                                   int* __restrict__ ctl) {
    __shared__ float sgw[NEXP * DDIM];  // 32 KB
    for (int i = threadIdx.x; i < NEXP * DDIM; i += 256) sgw[i] = gw[i];
    __syncthreads();
    int t = blockIdx.x * 256 + threadIdx.x;
    float acc[NEXP];
#pragma unroll
    for (int e = 0; e < NEXP; e++) acc[e] = 0.f;
    const float4* xr = (const float4*)(x + (size_t)t * DDIM);
    for (int q = 0; q < DDIM / 4; q++) {
        float4 v = xr[q];
#pragma unroll
        for (int e = 0; e < NEXP; e++) {
            float4 g = *(const float4*)&sgw[e * DDIM + q * 4];
            acc[e] += v.x * g.x + v.y * g.y + v.z * g.z + v.w * g.w;
        }
    }
    float m = acc[0];
#pragma unroll
    for (int e = 1; e < NEXP; e++) m = fmaxf(m, acc[e]);
    float p[NEXP]; float s = 0.f;
#pragma unroll
    for (int e = 0; e < NEXP; e++) { p[e] = __expf(acc[e] - m); s += p[e]; }
    float inv = 1.f / s;
    float best = -1.f, sec = -1.f; int bi = 0, si = 0;
#pragma unroll
    for (int e = 0; e < NEXP; e++) {
        float pe = p[e] * inv;
        if (pe > best) { sec = best; si = bi; best = pe; bi = e; }
        else if (pe > sec) { sec = pe; si = e; }
    }
    t2i[2 * t] = bi;  t2i[2 * t + 1] = si;
    t2w[2 * t] = best; t2w[2 * t + 1] = sec;
    atomicAdd(&ctl[bi], 1);
    atomicAdd(&ctl[si], 1);
}

// ---------------- schedule: prefix offsets + row-tile list (single thread) --------------
__global__ void schedule_kernel(int* ctl) {
    int* counts = ctl;
    int* cursors = ctl + 8;
    int* offs = ctl + 16;
    int* te = ctl + 32;
    int* tr = ctl + 112;
    int* ts = ctl + 192;
    int o = 0, tt = 0;
    for (int e = 0; e < NEXP; e++) {
        offs[e] = o;
        int n = counts[e];
        for (int r = 0; r < n; r += 128) { te[tt] = e; tr[tt] = o + r; ts[tt] = o + n; tt++; }
        cursors[e] = 0;
        o += n;
    }
    offs[8] = o;
    ctl[25] = tt;
}

// ---------------- scatter: assign slots ------------------------------------------------
__global__ __launch_bounds__(256) void scatter_kernel(const int* __restrict__ t2i,
                                                      const float* __restrict__ t2w,
                                                      int* ctl, int* __restrict__ slot_token,
                                                      float* __restrict__ slot_wt) {
    int t = blockIdx.x * 256 + threadIdx.x;
    int* cursors = ctl + 8;
    const int* offs = ctl + 16;
#pragma unroll
    for (int k = 0; k < 2; k++) {
        int e = t2i[2 * t + k];
        int pos = atomicAdd(&cursors[e], 1);
        int slot = offs[e] + pos;
        slot_token[slot] = t;
        slot_wt[slot] = t2w[2 * t + k];
    }
}

// ---------------- expert GEMMs ----------------------------------------------------------
// MODE 0: H=Xg@w1^T, G=Xg@w3^T (dual acc), A = silu(H)*G -> Abuf bf16.  BN=64.
// MODE 1: Y = Abuf@w2^T, epilogue unsafeAtomicAdd(w * Y) into y fp32.   BN=128.
// LDS T2 swizzle (both-sides, rule 21): staging groups are 8 rows x 8 chunks(16B);
// dest is linear (global_load_lds), SOURCE chunk = (lane&7)^(lane>>3) [row&7==lane>>3];
// READ chunk = (kk*4 + (lane>>4)) ^ (lane&7)  [all read-row bases are multiples of 8].
template <int MODE>
__global__ __launch_bounds__(256, 2) void moe_gemm_kernel(
    const u16* __restrict__ Amat, const u16* __restrict__ B1g, const u16* __restrict__ B2g,
    u16* __restrict__ OutB, float* __restrict__ OutY,
    const int* __restrict__ ctl, const int* __restrict__ slot_token,
    const float* __restrict__ slot_wt) {
    constexpr int BN = (MODE == 0) ? 64 : 128;
    constexpr int NB = BN / 32;   // B frags per wave
    constexpr int BL = BN / 32;   // B wave-loads per wave per K-step
    constexpr int BK = 64;
    constexpr int NK = DDIM / BK; // 16

    int tt = blockIdx.x;
    if (tt >= ctl[25]) return;
    int e = ctl[32 + tt];
    int rowbase = ctl[112 + tt];
    int segend = ctl[192 + tt];
    int cb = blockIdx.y;

    __shared__ __align__(16) u16 smem[2 * 128 * 64 + 2 * BN * 64 + ((MODE == 0) ? 2 * 64 * 64 : 0)];
    u16* sA = smem;                  // [2][128][64]
    u16* sB1 = smem + 2 * 128 * 64;  // [2][BN][64]
    u16* sB2 = sB1 + 2 * BN * 64;    // [2][64][64] (MODE 0 only)

    int tid = threadIdx.x;
    int lane = tid & 63;
    int wv = tid >> 6;
    int wrow = wv >> 1, wcol = wv & 1;
    int lr = lane >> 3;                          // row within 8-row staging group
    int lcs = ((lane & 7) ^ lr) * 8;             // pre-swizzled source chunk (elems)

    // Precompute gathered A source rows (4 staging loads per wave)
    size_t rowA[4];
#pragma unroll
    for (int i = 0; i < 4; i++) {
        int slot = rowbase + wv * 32 + i * 8 + lr;
        if (slot >= segend) slot = rowbase;
        int src = (MODE == 0) ? slot_token[slot] : slot;
        rowA[i] = (size_t)src * 1024;
    }
    size_t rowB[BL];
#pragma unroll
    for (int i = 0; i < BL; i++) {
        int r = cb * BN + wv * (BN / 4) + i * 8 + lr;
        rowB[i] = (size_t)e * 1048576 + (size_t)r * 1024;
    }

    f32x4 accH[4][NB], accG[4][NB];
    f32x4 zero = {0.f, 0.f, 0.f, 0.f};
#pragma unroll
    for (int m2 = 0; m2 < 4; m2++)
#pragma unroll
        for (int n = 0; n < NB; n++) { accH[m2][n] = zero; accG[m2][n] = zero; }

    auto stage = [&](int buf, int kt) {
        int k0 = kt * BK;
#pragma unroll
        for (int i = 0; i < 4; i++)
            gload16(Amat + rowA[i] + k0 + lcs, sA + (size_t)buf * (128 * 64) + (wv * 32 + i * 8) * 64);
#pragma unroll
        for (int i = 0; i < BL; i++)
            gload16(B1g + rowB[i] + k0 + lcs, sB1 + (size_t)buf * (BN * 64) + (wv * (BN / 4) + i * 8) * 64);
        if constexpr (MODE == 0) {
#pragma unroll
            for (int i = 0; i < BL; i++)
                gload16(B2g + rowB[i] + k0 + lcs, sB2 + (size_t)buf * (BN * 64) + (wv * (BN / 4) + i * 8) * 64);
        }
    };

    int l15 = lane & 15, hi = lane >> 4, l7 = lane & 7;

    auto compute = [&](int buf) {
#pragma unroll
        for (int kk = 0; kk < 2; kk++) {
            int cs = ((kk * 4 + hi) ^ l7) * 8;  // swizzled read chunk (elems)
            bf16x8 av[4];
#pragma unroll
            for (int m2 = 0; m2 < 4; m2++) {
                int r = wrow * 64 + m2 * 16 + l15;
                av[m2] = *(const bf16x8*)(sA + buf * (128 * 64) + r * 64 + cs);
            }
            bf16x8 b1v[NB];
#pragma unroll
            for (int n = 0; n < NB; n++) {
                int r = wcol * (BN / 2) + n * 16 + l15;
                b1v[n] = *(const bf16x8*)(sB1 + buf * (BN * 64) + r * 64 + cs);
            }
            if constexpr (MODE == 0) {
                bf16x8 b2v[NB];
#pragma unroll
                for (int n = 0; n < NB; n++) {
                    int r = wcol * (BN / 2) + n * 16 + l15;
                    b2v[n] = *(const bf16x8*)(sB2 + buf * (BN * 64) + r * 64 + cs);
                }
#pragma unroll
                for (int m2 = 0; m2 < 4; m2++)
#pragma unroll
                    for (int n = 0; n < NB; n++) {
                        accH[m2][n] = __builtin_amdgcn_mfma_f32_16x16x32_bf16(av[m2], b1v[n], accH[m2][n], 0, 0, 0);
                        accG[m2][n] = __builtin_amdgcn_mfma_f32_16x16x32_bf16(av[m2], b2v[n], accG[m2][n], 0, 0, 0);
                    }
            } else {
#pragma unroll
                for (int m2 = 0; m2 < 4; m2++)
#pragma unroll
                    for (int n = 0; n < NB; n++)
                        accH[m2][n] = __builtin_amdgcn_mfma_f32_16x16x32_bf16(av[m2], b1v[n], accH[m2][n], 0, 0, 0);
            }
        }
    };

    stage(0, 0);
    for (int kt = 0; kt < NK; ++kt) {
        __syncthreads();
        if (kt + 1 < NK) stage((kt + 1) & 1, kt + 1);
        compute(kt & 1);
    }

    // Epilogue. C/D layout: col = lane&15, row = (lane>>4)*4 + j  [learn_hip m89]
    int colblock = cb * BN + wcol * (BN / 2);
#pragma unroll
    for (int m2 = 0; m2 < 4; m2++) {
        int slotbase = rowbase + wrow * 64 + m2 * 16 + (lane >> 4) * 4;
#pragma unroll
        for (int n = 0; n < NB; n++) {
            int col = colblock + n * 16 + (lane & 15);
#pragma unroll
            for (int j = 0; j < 4; j++) {
                int slot = slotbase + j;
                if (slot < segend) {
                    if constexpr (MODE == 0) {
                        float h = accH[m2][n][j], g = accG[m2][n][j];
                        float a = (h / (1.f + __expf(-h))) * g;  // silu(h)*g
                        OutB[(size_t)slot * 1024 + col] = f2bf(a);
                    } else {
                        int tok = slot_token[slot];
                        float wgt = slot_wt[slot];
                        unsafeAtomicAdd(&OutY[(size_t)tok * 1024 + col], accH[m2][n][j] * wgt);
                    }
                }
            }
        }
    }
}

// ---------------- launch ----------------------------------------------------------------
extern "C" void kernel_launch(void* const* d_in, const int* in_sizes, int n_in,
                              void* d_out, int out_size, void* d_ws, size_t ws_size,
                              hipStream_t stream) {
    const float* x  = (const float*)d_in[0];
    const float* gw = (const float*)d_in[1];
    const float* w1 = (const float*)d_in[2];
    const float* w3 = (const float*)d_in[3];
    const float* w2 = (const float*)d_in[4];
    float* y = (float*)d_out;
    char* ws = (char*)d_ws;

    int*   ctl        = (int*)ws;                    // 4 KB control block
    int*   t2i        = (int*)(ws + 4096);           // 32 KB
    float* t2w        = (float*)(ws + 4096 + 32768);
    int*   slot_token = (int*)(ws + 4096 + 65536);
    float* slot_wt    = (float*)(ws + 4096 + 98304);
    u16*   xb   = (u16*)(ws + 262144);               // 4M elems
    u16*   w1b  = xb  + (size_t)4194304;             // 8M elems each
    u16*   w3b  = w1b + (size_t)8388608;
    u16*   w2b  = w3b + (size_t)8388608;
    u16*   Abuf = w2b + (size_t)8388608;             // 8192 x 1024 bf16

    hipMemsetAsync(ctl, 0, 4096, stream);
    hipMemsetAsync(y, 0, (size_t)out_size * sizeof(float), stream);

    cvt_all_kernel<<<2048, 256, 0, stream>>>(x, w1, w3, w2, xb);

    gate_kernel<<<16, 256, 0, stream>>>(x, gw, t2i, t2w, ctl);
    schedule_kernel<<<1, 1, 0, stream>>>(ctl);
    scatter_kernel<<<16, 256, 0, stream>>>(t2i, t2w, ctl, slot_token, slot_wt);

    moe_gemm_kernel<0><<<dim3(MAX_TILES, 16), 256, 0, stream>>>(
        xb, w1b, w3b, Abuf, nullptr, ctl, slot_token, slot_wt);
    moe_gemm_kernel<1><<<dim3(MAX_TILES, 8), 256, 0, stream>>>(
        Abuf, w2b, nullptr, nullptr, y, ctl, slot_token, slot_wt);
}